// Round 10
// baseline (52.517 us; speedup 1.0000x reference)
//
#include <hip/hip_runtime.h>

#define HH 256
#define WW 256
#define PLANE (HH * WW)          // 65536
#define CORE 32                  // output rows per strip (8 strips per image)
#define HALO 8                   // temporal halo rows (>= steps per launch)
#define SLAB 48                  // CORE + 2*HALO
#define NW 16                    // waves per block (1024 threads)
#define RPW 3                    // slab rows per wave (SLAB / NW)

// Horizontal neighbor exchange on the VALU pipe via gfx9 DPP wave shifts.
// bound_ctrl zero-fill gives the image-border zero-pad for free at lanes 0/63.
__device__ __forceinline__ float dpp_shfl_up1(float x) {   // lane i <- lane i-1; lane 0 <- 0
    return __int_as_float(__builtin_amdgcn_update_dpp(
        0, __float_as_int(x), 0x138 /*wave_shr:1*/, 0xf, 0xf, true));
}
__device__ __forceinline__ float dpp_shfl_dn1(float x) {   // lane i <- lane i+1; lane 63 <- 0
    return __int_as_float(__builtin_amdgcn_update_dpp(
        0, __float_as_int(x), 0x130 /*wave_shl:1*/, 0xf, 0xf, true));
}

// One step: read bank S (state s), write bank D (state s+1), publish D's
// boundary rows into parity buffer WR. Vertical in-wave neighbors read the
// intact old bank (no rolling carry / no old[] copies -> fewer v_movs).
template<int RD, int WR>
__device__ __forceinline__ void do_step(const float (&S)[RPW][4], float (&D)[RPW][4],
                                        const float (&pD)[RPW][4], const float (&pR)[RPW][4],
                                        float4 (*vt)[NW][64], float4 (*vb)[NW][64],
                                        int w, int lane)
{
    float upr[4] = {0.f, 0.f, 0.f, 0.f};
    float dnr[4] = {0.f, 0.f, 0.f, 0.f};
    if (w > 0)      { float4 v = vb[RD][w-1][lane]; upr[0]=v.x; upr[1]=v.y; upr[2]=v.z; upr[3]=v.w; }
    if (w < NW - 1) { float4 v = vt[RD][w+1][lane]; dnr[0]=v.x; dnr[1]=v.y; dnr[2]=v.z; dnr[3]=v.w; }

    #pragma unroll
    for (int dr = 0; dr < RPW; ++dr) {
        const float lf = dpp_shfl_up1(S[dr][3]);
        const float rt = dpp_shfl_dn1(S[dr][0]);
        #pragma unroll
        for (int c = 0; c < 4; ++c) {
            const float upv = dr ? S[dr-1][c] : upr[c];
            const float dnv = (dr < RPW - 1) ? S[dr+1][c] : dnr[c];
            const float lv  = c ? S[dr][c-1] : lf;
            const float rv  = (c < 3) ? S[dr][c+1] : rt;
            const float uc  = S[dr][c];
            const float s4  = (upv + dnv) + (lv + rv);
            const float lap = fmaf(-4.0f, uc, s4);
            const float g   = fmaf(-uc, uc, uc);          // uc*(1-uc)
            const float a   = fmaf(pD[dr][c], lap, uc);
            const float nv  = fmaf(pR[dr][c], g, a);
            D[dr][c] = __builtin_amdgcn_fmed3f(nv, 0.0f, 1.0f);
        }
    }
    vt[WR][w][lane] = make_float4(D[0][0], D[0][1], D[0][2], D[0][3]);
    vb[WR][w][lane] = make_float4(D[RPW-1][0], D[RPW-1][1], D[RPW-1][2], D[RPW-1][3]);
}

// R10: cut cells/CU/step (the convoy) 2x: halo 8 on core 32 -> 48-row slab
// (1.5x redundancy vs R5/R9's ~3x), 4 launches (8,8,8,7 steps). Register
// bank ping-pong kills the old[]/carry copies. LDS padded to 84 KB forces
// exactly 1 block/CU so no CU hosts a doubled convoy. Everything else
// (DPP horizontals, double-buffered LDS boundary rows, 1 barrier/step,
// trapezoid wave skip, dist-gated loads) carried over from the verified form.
__global__ __launch_bounds__(1024, 4)
void rd_bank_kernel(const float* __restrict__ uin,
                    const float* __restrict__ params,
                    const int* __restrict__ t,
                    float* __restrict__ uout,
                    int base, int k)
{
    __shared__ float4 vt[2][NW][64];   // each wave's row 0 (32 KB)
    __shared__ float4 vb[2][NW][64];   // each wave's row RPW-1 (32 KB)
    __shared__ int pad[5120];          // +20 KB -> 84 KB total: 1 block/CU

    const int blk   = blockIdx.x;
    const int b     = blk >> 3;          // image (8 strips per image)
    const int strip = blk & 7;
    const int r0    = strip * CORE;
    const int w     = threadIdx.x >> 6;  // wave = row-group, 0..15
    const int lane  = threadIdx.x & 63;  // lane = col-group (4 cols each)
    const int c0    = lane << 2;

    int ls = t[b] - base;
    ls = ls < 0 ? 0 : (ls > k ? k : ls);

    // keep pad alive (t values are in [0,32), so this never executes)
    if (t[0] == 0x7fffffff) pad[threadIdx.x & 4095] = ls;

    // wave's closest-row distance from the core slab band [HALO, HALO+CORE-1]
    const int tg = HALO - (RPW * w + RPW - 1);
    const int bg = RPW * w - (HALO + CORE - 1);
    int d_min = tg > bg ? tg : bg;
    if (d_min < 0) d_min = 0;
    int my_steps = ls - d_min;
    if (my_steps < 0) my_steps = 0;

    const int growbase = r0 - HALO + RPW * w;  // global row of this thread's dr=0
    const size_t ubase = (size_t)b * PLANE;
    const size_t pbase = (size_t)b * 2 * PLANE;

    float uA[RPW][4], uB[RPW][4], pD[RPW][4], pR[RPW][4];

    #pragma unroll
    for (int dr = 0; dr < RPW; ++dr) {
        const int grow = growbase + dr;
        const bool inimg = (grow >= 0) && (grow < HH);
        int dist = 0;
        if (grow < r0)                 dist = r0 - grow;
        else if (grow > r0 + CORE - 1) dist = grow - (r0 + CORE - 1);
        const bool needU = inimg && (dist <= ls);
        const bool needP = inimg && (dist < ls);

        if (needU) {
            const float4 uu = *reinterpret_cast<const float4*>(uin + ubase + (size_t)grow * WW + c0);
            uA[dr][0] = uu.x; uA[dr][1] = uu.y; uA[dr][2] = uu.z; uA[dr][3] = uu.w;
        } else {
            uA[dr][0] = uA[dr][1] = uA[dr][2] = uA[dr][3] = 0.f;
        }
        if (needP) {
            const float4 dd = *reinterpret_cast<const float4*>(params + pbase + (size_t)grow * WW + c0);
            const float4 rr = *reinterpret_cast<const float4*>(params + pbase + PLANE + (size_t)grow * WW + c0);
            pD[dr][0] = dd.x; pD[dr][1] = dd.y; pD[dr][2] = dd.z; pD[dr][3] = dd.w;
            pR[dr][0] = rr.x; pR[dr][1] = rr.y; pR[dr][2] = rr.z; pR[dr][3] = rr.w;
        } else {
            pD[dr][0] = pD[dr][1] = pD[dr][2] = pD[dr][3] = 0.f;
            pR[dr][0] = pR[dr][1] = pR[dr][2] = pR[dr][3] = 0.f;
        }
        uB[dr][0] = uB[dr][1] = uB[dr][2] = uB[dr][3] = 0.f;
    }

    if (ls > 0) {
        vt[0][w][lane] = make_float4(uA[0][0], uA[0][1], uA[0][2], uA[0][3]);
        vb[0][w][lane] = make_float4(uA[RPW-1][0], uA[RPW-1][1], uA[RPW-1][2], uA[RPW-1][3]);

        int s = 0;
        while (true) {
            __syncthreads();
            if (s < my_steps) do_step<0, 1>(uA, uB, pD, pR, vt, vb, w, lane);  // A -> B
            if (++s >= ls) break;
            __syncthreads();
            if (s < my_steps) do_step<1, 0>(uB, uA, pD, pR, vt, vb, w, lane);  // B -> A
            if (++s >= ls) break;
        }
    }

    // final state: uB if ls odd, uA if ls even (core waves never skip steps)
    #pragma unroll
    for (int dr = 0; dr < RPW; ++dr) {
        const int grow = growbase + dr;
        if (grow >= r0 && grow < r0 + CORE) {
            float4 o;
            if (ls & 1) o = make_float4(uB[dr][0], uB[dr][1], uB[dr][2], uB[dr][3]);
            else        o = make_float4(uA[dr][0], uA[dr][1], uA[dr][2], uA[dr][3]);
            *reinterpret_cast<float4*>(uout + ubase + (size_t)grow * WW + c0) = o;
        }
    }
}

extern "C" void kernel_launch(void* const* d_in, const int* in_sizes, int n_in,
                              void* d_out, int out_size, void* d_ws, size_t ws_size,
                              hipStream_t stream) {
    (void)in_sizes; (void)n_in; (void)out_size; (void)ws_size;
    const float* u      = (const float*)d_in[0];
    const float* params = (const float*)d_in[1];
    const int*   t      = (const int*)d_in[2];
    float*       out    = (float*)d_out;
    float*       ws     = (float*)d_ws;

    const dim3 grid(256), block(1024);
    // steps [0,8)->ws, [8,16)->out, [16,24)->ws, [24,31)->out
    rd_bank_kernel<<<grid, block, 0, stream>>>(u,   params, t, ws,  0,  8);
    rd_bank_kernel<<<grid, block, 0, stream>>>(ws,  params, t, out, 8,  8);
    rd_bank_kernel<<<grid, block, 0, stream>>>(out, params, t, ws,  16, 8);
    rd_bank_kernel<<<grid, block, 0, stream>>>(ws,  params, t, out, 24, 7);
}